// Round 4
// baseline (560.870 us; speedup 1.0000x reference)
//
#include <hip/hip_runtime.h>
#include <math.h>

#define N_ANGLES 180
#define P 724
#define W_IN 512

// ---------------- prep kernel: transpose + trig table ----------------
// ws[0..359] = {cos,sin} per angle (float2); ws+512 .. = transposed image
__global__ __launch_bounds__(256) void prep_all(const float* __restrict__ in,
                                                float* __restrict__ outT,
                                                float2* __restrict__ sc) {
    __shared__ float tile[32][33];
    const int bx = blockIdx.x * 32, by = blockIdx.y * 32;
    const int tx = threadIdx.x, ty = threadIdx.y;   // block (32,8)

    if (bx == 0 && by == 0) {
        int t = ty * 32 + tx;
        if (t < N_ANGLES) {
            float deg = (float)t * (180.0f / 179.0f);
            float ang = deg * (float)(M_PI / 180.0);
            sc[t] = make_float2(cosf(ang), sinf(ang));
        }
    }

    #pragma unroll
    for (int r = 0; r < 32; r += 8)
        tile[ty + r][tx] = in[(by + ty + r) * W_IN + bx + tx];
    __syncthreads();
    #pragma unroll
    for (int r = 0; r < 32; r += 8)
        outT[(bx + ty + r) * W_IN + by + tx] = tile[tx][ty + r];
}

// ---------------- main kernel ----------------
// Block = (angle a, 4 output rows i0..i0+3). 256 threads = 4 waves.
// Wave lane map: 16 consecutive j x 4 consecutive i  -> small rotated footprint
// (fewer cache lines per gather) while stores stay 64B-segment coalesced.
// MODE 2: trig+transpose from ws | MODE 1: trig only | MODE 0: standalone
template <int MODE>
__global__ __launch_bounds__(256) void radon_kernel(
    const float* __restrict__ x,       // [512,512]
    const float2* __restrict__ sc,     // [180] {c,s}
    const float* __restrict__ xT,      // [512,512] transposed (MODE==2)
    float* __restrict__ sino,          // [180,724]
    float* __restrict__ rot)           // [180,724,724]
{
    const int a  = blockIdx.y;             // angle
    const int i0 = blockIdx.x << 2;        // row quad (181 * 4 == 724)
    const int tid = threadIdx.x;
    const int w  = tid >> 6;               // wave 0..3
    const int l  = tid & 63;
    const int il = l >> 4;                 // 0..3  (row within quad)
    const int jl = l & 15;                 // 0..15 (col within 16-seg)
    const int i  = i0 + il;

    float c, s;
    if (MODE > 0) {
        float2 cs = sc[a];
        c = cs.x; s = cs.y;
    } else {
        float deg = (float)a * (180.0f / 179.0f);
        float ang = deg * (float)(M_PI / 180.0);
        c = cosf(ang); s = sinf(ang);
    }

    // ix = c*j + Kx, iy = s*j + Ky  (unpadded input coords; PAD folded in)
    const float fi = (float)i - 361.5f;
    const float Kx = 255.5f - 361.5f * c - s * fi;
    const float Ky = 255.5f - 361.5f * s + c * fi;

    // block-uniform axis swap: fast axis = contiguous in the gathered image
    const bool useT = (MODE == 2) && (fabsf(s) > fabsf(c));
    const float* __restrict__ bimg = useT ? xT : x;
    const float fcoef = useT ? s : c;
    const float scoef = useT ? c : s;
    const float fK    = useT ? Ky : Kx;
    const float sK    = useT ? Kx : Ky;

    const int jbase = (w << 4) + jl;       // wave w covers [w*16, w*16+16) per 64-window
    float fcv = fmaf((float)jbase, fcoef, fK);
    float scv = fmaf((float)jbase, scoef, sK);
    const float fstep = 64.0f * fcoef;
    const float sstep = 64.0f * scoef;

    float* __restrict__ rbase = rot + (size_t)(a * P + i) * P;
    float lsum = 0.0f;

    // 12 iterations cover j in [0, 768); mask j<724
    for (int it = 0; it < 12; ++it) {
        const int j = jbase + (it << 6);
        const bool valid = (j < P);
        // nonzero sample requires both coords in open interval (-1, 512) (exact)
        const bool live = valid && (fcv > -1.0f) && (fcv < 512.0f)
                                && (scv > -1.0f) && (scv < 512.0f);
        float val = 0.0f;
        if (__any((int)live)) {
            const float f0f = floorf(fcv), s0f = floorf(scv);
            const int f0 = (int)f0f, s0 = (int)s0f;
            const float wf1 = fcv - f0f, wf0 = 1.0f - wf1;
            const float ws1 = scv - s0f, ws0 = 1.0f - ws1;
            const bool inter = live && ((unsigned)f0 < 511u) && ((unsigned)s0 < 511u);
            if (__all((int)inter)) {
                // fully interior wave: one base, imm-offset taps
                const float* bp = bimg + (s0 << 9) + f0;
                const float v00 = bp[0],   vA  = bp[1];
                const float vB  = bp[512], v11 = bp[513];
                val = fmaf(ws1, fmaf(wf1, v11, wf0 * vB),
                           ws0 * fmaf(wf1, vA, wf0 * v00));
            } else {
                // boundary/mixed wave: fold oob masks into weights, clamp indices
                const int fb = f0 + 1, sb = s0 + 1;
                const float a0 = ((unsigned)f0 < 512u) ? wf0 : 0.0f;
                const float a1 = ((unsigned)fb < 512u) ? wf1 : 0.0f;
                const float b0 = ((unsigned)s0 < 512u) ? ws0 : 0.0f;
                const float b1 = ((unsigned)sb < 512u) ? ws1 : 0.0f;
                const int fca = min(max(f0, 0), 511);
                const int fcb = min(max(fb, 0), 511);
                const int sca = min(max(s0, 0), 511);
                const int scb = min(max(sb, 0), 511);
                const float v00 = bimg[(sca << 9) + fca];
                const float v01 = bimg[(sca << 9) + fcb];
                const float v10 = bimg[(scb << 9) + fca];
                const float v11 = bimg[(scb << 9) + fcb];
                val = fmaf(b1, fmaf(a1, v11, a0 * v10),
                           b0 * fmaf(a1, v01, a0 * v00));
            }
        }
        if (valid) {
            __builtin_nontemporal_store(val, rbase + j);
            lsum += val;
        }
        fcv += fstep;
        scv += sstep;
    }

    // sinogram: reduce within 16-lane row groups, then across the 4 waves
    for (int off = 8; off > 0; off >>= 1)
        lsum += __shfl_down(lsum, off, 16);

    __shared__ float red[16];
    if (jl == 0) red[(w << 2) | il] = lsum;
    __syncthreads();
    if (tid < 4)
        sino[a * P + i0 + tid] = red[tid] + red[4 + tid] + red[8 + tid] + red[12 + tid];
}

// ---------------- launch ----------------

extern "C" void kernel_launch(void* const* d_in, const int* in_sizes, int n_in,
                              void* d_out, int out_size, void* d_ws, size_t ws_size,
                              hipStream_t stream) {
    const float* x = (const float*)d_in[0];
    float* sino = (float*)d_out;                       // [180*724]
    float* rot  = sino + (size_t)N_ANGLES * P;         // [180*724*724]
    float* ws   = (float*)d_ws;

    const dim3 grid(P / 4, N_ANGLES), blk(256);
    if (ws && ws_size >= (size_t)(512 + 512 * 512) * sizeof(float)) {
        float* xT = ws + 512;
        prep_all<<<dim3(16, 16), dim3(32, 8), 0, stream>>>(x, xT, (float2*)ws);
        radon_kernel<2><<<grid, blk, 0, stream>>>(x, (const float2*)ws, xT, sino, rot);
    } else if (ws && ws_size >= (size_t)512 * sizeof(float)) {
        prep_all<<<dim3(16, 16), dim3(32, 8), 0, stream>>>(x, nullptr, (float2*)ws); // trig only
        radon_kernel<1><<<grid, blk, 0, stream>>>(x, (const float2*)ws, nullptr, sino, rot);
    } else {
        radon_kernel<0><<<grid, blk, 0, stream>>>(x, nullptr, nullptr, sino, rot);
    }
}

// Round 6
// 453.946 us; speedup vs baseline: 1.2355x; 1.2355x over previous
//
#include <hip/hip_runtime.h>
#include <math.h>

#define N_ANGLES 180
#define P 724
#define W_IN 512
#define PSTRIDE 520      // padded row stride (floats)
#define PROWS 516        // padded rows

// ---------------- prep: trig table + zero-padded image + padded transpose ----
// ws[0..359] = {cos,sin}; img0 = ws+512 (516x520, zero ring at border);
// imgT = img0 + 516*520 (transposed copy, same padding).
__global__ __launch_bounds__(256) void prep_pad(const float* __restrict__ in,
                                                float* __restrict__ img0,
                                                float* __restrict__ imgT,
                                                float2* __restrict__ sc) {
    if (blockIdx.x == 0 && blockIdx.y == 0) {
        int t = threadIdx.x;
        if (t < N_ANGLES) {
            float deg = (float)t * (180.0f / 179.0f);
            float ang = deg * (float)(M_PI / 180.0);
            sc[t] = make_float2(cosf(ang), sinf(ang));
        }
    }
    const int xcol = blockIdx.x * 32 + (threadIdx.x & 31);
    const int yrow = blockIdx.y * 8 + (threadIdx.x >> 5);
    if (xcol < PSTRIDE && yrow < PROWS) {
        const unsigned xi = (unsigned)(xcol - 1), yi = (unsigned)(yrow - 1);
        const bool inb = (xi < 512u) && (yi < 512u);
        img0[yrow * PSTRIDE + xcol] = inb ? in[yi * 512u + xi] : 0.0f;
        imgT[yrow * PSTRIDE + xcol] = inb ? in[xi * 512u + yi] : 0.0f;
    }
}

__global__ __launch_bounds__(256) void prep_trig(float2* __restrict__ sc) {
    int t = threadIdx.x;
    if (t < N_ANGLES) {
        float deg = (float)t * (180.0f / 179.0f);
        float ang = deg * (float)(M_PI / 180.0);
        sc[t] = make_float2(cosf(ang), sinf(ang));
    }
}

// ---------------- main kernel ----------------
// Block = one output row (a, i). 256 threads; lane <-> consecutive j
// (full-wave 256B contiguous stores -- the R1 layout that measured best).
// MODE 2: padded images (no bounds logic) | MODE 1: trig table | MODE 0: standalone
template <int MODE>
__global__ __launch_bounds__(256) void radon_kernel(
    const float* __restrict__ x,       // [512,512] (MODE<2 sampling source)
    const float2* __restrict__ sc,     // [180] {c,s}
    const float* __restrict__ img0,    // padded [516,520] (MODE==2)
    const float* __restrict__ imgT,    // padded transposed (MODE==2)
    float* __restrict__ sino,          // [180,724]
    float* __restrict__ rot)           // [180,724,724]
{
    const int a = blockIdx.y;
    const int i = blockIdx.x;
    const int tid = threadIdx.x;

    float c, s;
    if (MODE > 0) {
        float2 cs = sc[a];
        c = cs.x; s = cs.y;
    } else {
        float deg = (float)a * (180.0f / 179.0f);
        float ang = deg * (float)(M_PI / 180.0);
        c = cosf(ang); s = sinf(ang);
    }

    // ix = c*j + Kx, iy = s*j + Ky  (unpadded input coords; PAD folded in)
    const float fi = (float)i - 361.5f;
    const float Kx = 255.5f - 361.5f * c - s * fi;
    const float Ky = 255.5f - 361.5f * s + c * fi;

    // block-uniform axis swap: fast axis = contiguous in the gathered image
    const bool useT = (MODE == 2) && (fabsf(s) > fabsf(c));
    const float* __restrict__ img = (MODE == 2) ? (useT ? imgT : img0) : x;
    const float fcoef = useT ? s : c;
    const float scoef = useT ? c : s;
    const float fK    = useT ? Ky : Kx;
    const float sK    = useT ? Kx : Ky;

    // ---- analytic nonzero span: sample != 0 requires ix,iy in (-1,512) ----
    float lo = 0.0f, hi = 723.0f;
    bool empty = false;
    if (fabsf(c) >= 1e-3f) {
        float r = 1.0f / c;
        float b1 = (-1.0f - Kx) * r, b2 = (512.0f - Kx) * r;
        lo = fmaxf(lo, fminf(b1, b2)); hi = fminf(hi, fmaxf(b1, b2));
    } else if (Kx <= -1.0f || Kx >= 512.0f) empty = true;
    if (fabsf(s) >= 1e-3f) {
        float r = 1.0f / s;
        float b1 = (-1.0f - Ky) * r, b2 = (512.0f - Ky) * r;
        lo = fmaxf(lo, fminf(b1, b2)); hi = fminf(hi, fmaxf(b1, b2));
    } else if (Ky <= -1.0f || Ky >= 512.0f) empty = true;
    int jlo = 1, jhi = 0;
    if (!empty && lo <= hi) {
        jlo = max(0, (int)floorf(lo) - 2);    // widen 2px: covers fp boundary error
        jhi = min(723, (int)ceilf(hi) + 2);
    }

    float* __restrict__ rrow = rot + (size_t)(a * P + i) * P;
    float lsum = 0.0f;

    #pragma unroll
    for (int it = 0; it < 3; ++it) {
        const int j = tid + (it << 8);
        if (j < P) {
            float val = 0.0f;
            // window-level span test (block-uniform): skip all math for dead windows
            const bool winlive = (jlo <= (it << 8) + 255) && (jhi >= (it << 8));
            if (winlive) {
                const float jf = (float)j;
                const float fcv = fmaf(jf, fcoef, fK);
                const float scv = fmaf(jf, scoef, sK);
                const bool live = (fcv > -1.0f) && (fcv < 512.0f)
                               && (scv > -1.0f) && (scv < 512.0f);
                const float f0f = floorf(fcv), s0f = floorf(scv);
                const float wf1 = fcv - f0f, wf0 = 1.0f - wf1;
                const float ws1 = scv - s0f, ws0 = 1.0f - ws1;

                if (MODE == 2) {
                    // padded coords: live taps always in-bounds; clamp only for dead lanes
                    int f0 = min(max((int)f0f + 1, 0), 512);
                    int s0 = min(max((int)s0f + 1, 0), 512);
                    const float* bp = img + s0 * PSTRIDE + f0;
                    const float v00 = bp[0],       v01 = bp[1];
                    const float v10 = bp[PSTRIDE], v11 = bp[PSTRIDE + 1];
                    float v = fmaf(ws1, fmaf(wf1, v11, wf0 * v10),
                                   ws0 * fmaf(wf1, v01, wf0 * v00));
                    val = live ? v : 0.0f;
                } else {
                    // fallback: bounds-checked on the raw 512x512 image
                    const int f0 = (int)f0f, s0 = (int)s0f;
                    const int fb = f0 + 1, sb = s0 + 1;
                    const float a0 = ((unsigned)f0 < 512u) ? wf0 : 0.0f;
                    const float a1 = ((unsigned)fb < 512u) ? wf1 : 0.0f;
                    const float b0 = ((unsigned)s0 < 512u) ? ws0 : 0.0f;
                    const float b1 = ((unsigned)sb < 512u) ? ws1 : 0.0f;
                    const int fca = min(max(f0, 0), 511);
                    const int fcb = min(max(fb, 0), 511);
                    const int sca = min(max(s0, 0), 511);
                    const int scb = min(max(sb, 0), 511);
                    const float v00 = img[(sca << 9) + fca];
                    const float v01 = img[(sca << 9) + fcb];
                    const float v10 = img[(scb << 9) + fca];
                    const float v11 = img[(scb << 9) + fcb];
                    val = fmaf(b1, fmaf(a1, v11, a0 * v10),
                               b0 * fmaf(a1, v01, a0 * v00));
                }
            }
            __builtin_nontemporal_store(val, rrow + j);
            lsum += val;
        }
    }

    // block reduction: wave64 shuffle, then cross-wave via LDS (4 waves)
    for (int off = 32; off > 0; off >>= 1)
        lsum += __shfl_down(lsum, off, 64);

    __shared__ float ws_red[4];
    const int lane = tid & 63;
    const int wid  = tid >> 6;
    if (lane == 0) ws_red[wid] = lsum;
    __syncthreads();
    if (tid == 0)
        sino[a * P + i] = ws_red[0] + ws_red[1] + ws_red[2] + ws_red[3];
}

// ---------------- launch ----------------

extern "C" void kernel_launch(void* const* d_in, const int* in_sizes, int n_in,
                              void* d_out, int out_size, void* d_ws, size_t ws_size,
                              hipStream_t stream) {
    const float* x = (const float*)d_in[0];
    float* sino = (float*)d_out;                       // [180*724]
    float* rot  = sino + (size_t)N_ANGLES * P;         // [180*724*724]
    float* ws   = (float*)d_ws;

    const size_t PADFLOATS = (size_t)PROWS * PSTRIDE;
    const size_t need2 = (512 + 2 * PADFLOATS) * sizeof(float);   // ~2.05 MB

    const dim3 grid(P, N_ANGLES), blk(256);
    if (ws && ws_size >= need2) {
        float* img0 = ws + 512;
        float* imgT = img0 + PADFLOATS;
        prep_pad<<<dim3(17, 65), dim3(256), 0, stream>>>(x, img0, imgT, (float2*)ws);
        radon_kernel<2><<<grid, blk, 0, stream>>>(x, (const float2*)ws, img0, imgT, sino, rot);
    } else if (ws && ws_size >= 512 * sizeof(float)) {
        prep_trig<<<dim3(1), dim3(256), 0, stream>>>((float2*)ws);
        radon_kernel<1><<<grid, blk, 0, stream>>>(x, (const float2*)ws, nullptr, nullptr, sino, rot);
    } else {
        radon_kernel<0><<<grid, blk, 0, stream>>>(x, nullptr, nullptr, nullptr, sino, rot);
    }
}